// Round 9
// baseline (101.780 us; speedup 1.0000x reference)
//
#include <hip/hip_runtime.h>

typedef _Float16 f16;
typedef _Float16 f16x2 __attribute__((ext_vector_type(2)));
typedef _Float16 f16x4 __attribute__((ext_vector_type(4)));
typedef _Float16 f16x8 __attribute__((ext_vector_type(8)));
typedef float    f32x4 __attribute__((ext_vector_type(4)));
typedef unsigned int u32;

#define LOG2E 1.44269504088896340736f

__device__ __forceinline__ f16x2 habs2(f16x2 v) {
    union { f16x2 h; u32 u; } x; x.h = v; x.u &= 0x7FFF7FFFu; return x.h;
}
#if __has_builtin(__builtin_amdgcn_fdot2)
__device__ __forceinline__ float fdot2f(f16x2 a, f16x2 b, float c) {
    return __builtin_amdgcn_fdot2(a, b, c, false);
}
#else
__device__ __forceinline__ float fdot2f(f16x2 a, f16x2 b, float c) {
    return c + (float)a.x * (float)b.x + (float)a.y * (float)b.y;
}
#endif
#if __has_builtin(__builtin_amdgcn_exp2f)
#define EXP2F __builtin_amdgcn_exp2f
#else
#define EXP2F exp2f
#endif

// ---------------------------------------------------------------------------
// K1: projections directly from f32 (no transpose kernel): W[k*128+col] is
// coalesced across col. f32 FMA accumulate, f16 round only at store.
// grid 256 x 384; block = 4 nodes; t>>7 selects W_l/W_r/W_v, t&127 = column.
// Outputs:
//   Wlh f16 [j][128]                 (o = h*32+d)
//   WrL f16 [4h][8c][1024 j][4 l]    (d = 4c+l; coalesced K2 phase-1 loads)
//   VL  f16 [4h][32 d][1024 j]       (MFMA B-frag: 8 contiguous j at fixed d)
// ---------------------------------------------------------------------------
__global__ __launch_bounds__(384) void k1_proj(
        const float* __restrict__ h,  const float* __restrict__ Wl,
        const float* __restrict__ Wr, const float* __restrict__ Wv,
        f16* __restrict__ Wlh, f16* __restrict__ WrL, f16* __restrict__ VL) {
    __shared__ float hs[4][128];
    const int t = threadIdx.x, i0 = blockIdx.x * 4;
    for (int idx = t; idx < 512; idx += 384)
        hs[idx >> 7][idx & 127] = h[(i0 + (idx >> 7)) * 128 + (idx & 127)];
    __syncthreads();

    const int wsel = t >> 7, col = t & 127;
    const float* W = (wsel == 0) ? Wl : ((wsel == 1) ? Wr : Wv);
    float a0 = 0.f, a1 = 0.f, a2 = 0.f, a3 = 0.f;
    #pragma unroll 8
    for (int k = 0; k < 128; k++) {
        float wv = W[k * 128 + col];
        a0 += hs[0][k] * wv; a1 += hs[1][k] * wv;
        a2 += hs[2][k] * wv; a3 += hs[3][k] * wv;
    }
    float accs[4] = {a0, a1, a2, a3};
    const int hh = col >> 5, dd = col & 31, c = dd >> 2, l = dd & 3;
    #pragma unroll
    for (int i = 0; i < 4; i++) {
        int j = i0 + i;
        f16 hv = (f16)accs[i];
        if (wsel == 0)      Wlh[j * 128 + col] = hv;
        else if (wsel == 1) WrL[((hh * 8 + c) * 1024 + j) * 4 + l] = hv;
        else                VL[(hh * 32 + dd) * 1024 + j] = hv;
    }
}

// ---------------------------------------------------------------------------
// K2: fused GATv2 attention + MFMA aggregation + LayerNorm + ReLU.
// grid 256 x 1024 (16 waves). Block = 4 nodes. Wave w -> (head hh = w&3,
// j-quarter = w>>2) — 2x wave parallelism vs round 8 to hide L2 latency
// (phase 1 is VALU-throughput-bound at ~3.4 us/CU; the rest was latency).
// LDS 41 KB. lrelu identity: a.lrelu(t) = (0.6a).t + (0.4a).|t|.
// ---------------------------------------------------------------------------
__global__ __launch_bounds__(1024, 4) void GATv2Layer_84447646974220_kernel(
        const f16* __restrict__ Wlh, const f16* __restrict__ WrL,
        const f16* __restrict__ VL,  const int* __restrict__ adj,
        const float* __restrict__ a_, const float* __restrict__ ln_g,
        const float* __restrict__ ln_b, float* __restrict__ out) {

    __shared__ __align__(16) f16 ep[4][4][1024];   // [head][row][j]  32768 B
    __shared__ float aggS[4][4][128];              // [quar][row][col] 8192 B
    __shared__ float redM[4][4][4];                // [quar][head][row]
    __shared__ float redS[4][4][4];

    const int t    = threadIdx.x;
    const int w    = t >> 6;        // 0..15
    const int lane = t & 63;
    const int hh   = w & 3;         // head
    const int quar = w >> 2;        // j-quarter (256 j each)
    const int i0   = blockIdx.x * 4;

    // per-wave constants: p2 = 0.6*a, q2 = 0.4*a (f16 pairs), Wl head-slices
    f16x2 p2[16], q2[16];
    #pragma unroll
    for (int d2 = 0; d2 < 16; d2++) {
        float a0 = a_[2 * d2], a1 = a_[2 * d2 + 1];
        f16x2 p; p.x = (f16)(0.6f * a0); p.y = (f16)(0.6f * a1);
        f16x2 q; q.x = (f16)(0.4f * a0); q.y = (f16)(0.4f * a1);
        p2[d2] = p; q2[d2] = q;
    }
    f16x2 wl2[4][16];
    #pragma unroll
    for (int ii = 0; ii < 4; ii++) {
        const f16x2* src = (const f16x2*)(Wlh + (i0 + ii) * 128 + hh * 32);
        #pragma unroll
        for (int c2 = 0; c2 < 16; c2++) wl2[ii][c2] = src[c2];
    }

    // ---- phase 1: scores e[i][j] for this wave's (head, quarter) ----
    float maxE[4];
    #pragma unroll
    for (int ii = 0; ii < 4; ii++) maxE[ii] = -__builtin_inff();

    #pragma unroll 1
    for (int jb = 0; jb < 4; jb++) {
        int j = quar * 256 + jb * 64 + lane;
        f16x4 wr[8];
        #pragma unroll
        for (int c = 0; c < 8; c++)
            wr[c] = *(const f16x4*)(WrL + ((hh * 8 + c) * 1024 + j) * 4);
        int am[4];
        #pragma unroll
        for (int ii = 0; ii < 4; ii++) am[ii] = adj[(i0 + ii) * 1024 + j];

        float e[4] = {0.f, 0.f, 0.f, 0.f};
        #pragma unroll
        for (int c = 0; c < 8; c++) {
            #pragma unroll
            for (int ii = 0; ii < 4; ii++) {
                f16x2 t0 = wl2[ii][2 * c]     + wr[c].lo;
                f16x2 t1 = wl2[ii][2 * c + 1] + wr[c].hi;
                e[ii] = fdot2f(p2[2 * c],     t0, e[ii]);
                e[ii] = fdot2f(q2[2 * c],     habs2(t0), e[ii]);
                e[ii] = fdot2f(p2[2 * c + 1], t1, e[ii]);
                e[ii] = fdot2f(q2[2 * c + 1], habs2(t1), e[ii]);
            }
        }
        #pragma unroll
        for (int ii = 0; ii < 4; ii++) {
            float v = am[ii] ? e[ii] : -__builtin_inff();
            maxE[ii] = fmaxf(maxE[ii], v);
            ep[hh][ii][j] = (f16)v;
        }
    }

    // ---- phase 2: softmax (cross-quarter max/sum through LDS) ----
    #pragma unroll
    for (int ii = 0; ii < 4; ii++) {
        float M = maxE[ii];
        #pragma unroll
        for (int off = 32; off > 0; off >>= 1) M = fmaxf(M, __shfl_xor(M, off));
        if (lane == 0) redM[quar][hh][ii] = M;
    }
    __syncthreads();

    #pragma unroll
    for (int ii = 0; ii < 4; ii++) {
        float M = fmaxf(fmaxf(redM[0][hh][ii], redM[1][hh][ii]),
                        fmaxf(redM[2][hh][ii], redM[3][hh][ii]));
        f16x4 v0 = *(f16x4*)&ep[hh][ii][quar * 256 + lane * 4];
        float pb[4], l = 0.f;
        #pragma unroll
        for (int e = 0; e < 4; e++) pb[e] = EXP2F(((float)v0[e] - M) * LOG2E);
        #pragma unroll
        for (int e = 0; e < 4; e++) { v0[e] = (f16)pb[e]; l += pb[e]; }
        *(f16x4*)&ep[hh][ii][quar * 256 + lane * 4] = v0;
        #pragma unroll
        for (int off = 32; off > 0; off >>= 1) l += __shfl_xor(l, off);
        if (lane == 0) redS[quar][hh][ii] = l;
    }
    __syncthreads();

    float lr[4];
    #pragma unroll
    for (int ii = 0; ii < 4; ii++)
        lr[ii] = 1.0f / (redS[0][hh][ii] + redS[1][hh][ii] +
                         redS[2][hh][ii] + redS[3][hh][ii]);

    // ---- phase 3: agg = p @ V via MFMA (this wave's 256-j slice) ----
    // A-frag: A[m=lane&15][k=(lane>>4)*8+jj]; rows 4..15 duplicate rows 0..3
    // (garbage C-rows discarded). B-frag from VL[d=n][j=k] (contiguous j).
    // C/D: col=lane&15, row=(lane>>4)*4+reg -> rows 0..3 live in quad 0.
    f32x4 acc0 = {0.f, 0.f, 0.f, 0.f}, acc1 = {0.f, 0.f, 0.f, 0.f};
    const int q8  = (lane >> 4) << 3;
    const int m3  = lane & 3;
    const int n15 = lane & 15;

    #pragma unroll
    for (int jt2 = 0; jt2 < 2; jt2++) {
        int jt = quar * 2 + jt2;
        #pragma unroll
        for (int kk = 0; kk < 4; kk++) {
            int ko = jt * 128 + kk * 32 + q8;
            f16x8 af = *(const f16x8*)&ep[hh][m3][ko];
            f16x8 b0 = *(const f16x8*)(VL + (hh * 32 + n15) * 1024 + ko);
            f16x8 b1 = *(const f16x8*)(VL + (hh * 32 + 16 + n15) * 1024 + ko);
            acc0 = __builtin_amdgcn_mfma_f32_16x16x32_f16(af, b0, acc0, 0, 0, 0);
            acc1 = __builtin_amdgcn_mfma_f32_16x16x32_f16(af, b1, acc1, 0, 0, 0);
        }
    }

    if (lane < 16) {
        #pragma unroll
        for (int r = 0; r < 4; r++) {
            aggS[quar][r][hh * 32 + lane]      = acc0[r] * lr[r];
            aggS[quar][r][hh * 32 + 16 + lane] = acc1[r] * lr[r];
        }
    }
    __syncthreads();

    // ---- phase 4: LayerNorm + ReLU (waves 0..3, one node-row each) ----
    if (w < 4) {
        float x0 = aggS[0][w][lane]      + aggS[1][w][lane] +
                   aggS[2][w][lane]      + aggS[3][w][lane];
        float x1 = aggS[0][w][lane + 64] + aggS[1][w][lane + 64] +
                   aggS[2][w][lane + 64] + aggS[3][w][lane + 64];
        float s = x0 + x1, sq = x0 * x0 + x1 * x1;
        #pragma unroll
        for (int off = 32; off > 0; off >>= 1) {
            s  += __shfl_xor(s, off);
            sq += __shfl_xor(sq, off);
        }
        float mean = s * (1.f / 128.f);
        float var  = sq * (1.f / 128.f) - mean * mean;
        float rs   = rsqrtf(var + 1e-5f);
        float y0 = fmaxf((x0 - mean) * rs * ln_g[lane]      + ln_b[lane],      0.f);
        float y1 = fmaxf((x1 - mean) * rs * ln_g[lane + 64] + ln_b[lane + 64], 0.f);
        out[(i0 + w) * 128 + lane]      = y0;
        out[(i0 + w) * 128 + 64 + lane] = y1;
    }
}

// ---------------------------------------------------------------------------
extern "C" void kernel_launch(void* const* d_in, const int* in_sizes, int n_in,
                              void* d_out, int out_size, void* d_ws, size_t ws_size,
                              hipStream_t stream) {
    const float* h   = (const float*)d_in[0];
    const int*   adj = (const int*)d_in[1];
    const float* Wl  = (const float*)d_in[2];
    const float* Wr  = (const float*)d_in[3];
    const float* Wv  = (const float*)d_in[4];
    const float* a_  = (const float*)d_in[5];
    const float* g_  = (const float*)d_in[6];
    const float* b_  = (const float*)d_in[7];
    float* out = (float*)d_out;

    char* ws = (char*)d_ws;
    f16* Wlh = (f16*)(ws);                 // 1024*128 f16    = 262144 B
    f16* WrL = (f16*)(ws + 262144);        // [4][8][1024][4] = 262144 B
    f16* VL  = (f16*)(ws + 524288);        // [4][32][1024]   = 262144 B

    k1_proj<<<256, 384, 0, stream>>>(h, Wl, Wr, Wv, Wlh, WrL, VL);
    GATv2Layer_84447646974220_kernel<<<256, 1024, 0, stream>>>(
        Wlh, WrL, VL, adj, a_, g_, b_, out);
}